// Round 5
// baseline (360.536 us; speedup 1.0000x reference)
//
#include <hip/hip_runtime.h>

// FusionAttentionBlock: algebraic reduction.
//   G11=x1'x1, G12=x1'x2, G22=x2'x2, s1,s2 = colsums  (pass 1, MFMA bf16; G12 hi/lo split)
//   S = Wq G12 Wk' + (Wq s1) bk' + bq (Wk s2)' + B bq bk';  attn = softmax(S)
//   M = attn Wv', A = I + W' M, c = b@M + bv;  BN moments from G,s  ->  A'', c''
//   y = x @ A'' + c''                                        (pass 3, MFMA bf16 x-hi only)

#define NCHUNK 16384        // 524288 rows / 32 rows per chunk
#define GRAM_FLOATS 49152   // 3 * 128 * 128
#define GRAM_F4 12288
#define RSEG 8

typedef __attribute__((ext_vector_type(4))) float f32x4;
typedef __attribute__((ext_vector_type(8))) short s16x8;

__device__ __forceinline__ unsigned bf16rn(float f){
  unsigned x = __float_as_uint(f);
  return (x + 0x7FFFu + ((x >> 16) & 1u)) >> 16;
}

// two floats -> packed bf16-hi word and bf16-lo (residual) word
__device__ __forceinline__ uint2 hilo2(float a, float b){
  unsigned ha = bf16rn(a), hb = bf16rn(b);
  float la = a - __uint_as_float(ha << 16);
  float lb = b - __uint_as_float(hb << 16);
  return make_uint2(ha | (hb << 16), bf16rn(la) | (bf16rn(lb) << 16));
}

__device__ __forceinline__ s16x8 u4_frag(uint4 v){
  union { uint4 u; s16x8 s; } cv; cv.u = v; return cv.s;
}

// Barrier that does NOT drain vmcnt: LDS ordering only. Prefetch global loads
// issued before this barrier stay in flight (counted vmcnt waits appear only at
// their register uses, ~2 chunks later).
__device__ __forceinline__ void block_sync_lds(){
  asm volatile("s_waitcnt lgkmcnt(0)" ::: "memory");
  __builtin_amdgcn_s_barrier();
  __builtin_amdgcn_sched_barrier(0);
}

// LDS per array: [128 cols][32 rows bf16 = 64B]; 16B chunks XOR-swizzled so both
// the column-major staging writes and the frag reads tile banks.
__device__ __forceinline__ unsigned lds_off(int c, int g){
  return (unsigned)(c * 64 + ((g ^ ((c >> 1) & 3)) << 4));
}

__device__ __forceinline__ s16x8 lds_frag(const char* base, int tile, int lane){
  int c = tile * 16 + (lane & 15);
  int g = lane >> 4;
  return *reinterpret_cast<const s16x8*>(base + lds_off(c, g));
}

// ---------------- pass 1: partial Gram matrices ----------------
// 512 thr = 8 waves in a 4x2 grid; wave owns 32 rows x 64 cols of each Gram.
__global__ __launch_bounds__(512) void k_gram(const float* __restrict__ x1,
                                              const float* __restrict__ x2,
                                              float* __restrict__ partG,
                                              float* __restrict__ partS,
                                              int NB)
{
  __shared__ __align__(16) char lds[65536];   // 2 buffers x 4 arrays x 8KB
  const int t    = threadIdx.x;
  const int lane = t & 63;
  const int w    = t >> 6;
  const int wr   = w >> 1;     // wave row 0..3  (rows wr*32..wr*32+31)
  const int wc   = w & 1;      // wave col 0..1  (cols wc*64..wc*64+63)
  const int c    = t & 127;    // staging column (feature)
  const int g4   = t >> 7;     // staging row-group (rows g4*8..g4*8+7)
  const int b    = blockIdx.x;

  const f32x4 zero4 = {0.f, 0.f, 0.f, 0.f};
  f32x4 acc[3][2][4];
#pragma unroll
  for (int m3 = 0; m3 < 3; ++m3)
#pragma unroll
    for (int ri = 0; ri < 2; ++ri)
#pragma unroll
      for (int ci = 0; ci < 4; ++ci) acc[m3][ri][ci] = zero4;

  float s1a = 0.f, s2a = 0.f;
  float vA1[8], vA2[8], vB1[8], vB2[8];

  const unsigned offst = lds_off(c, g4);

  auto loadA = [&](int ch){
    const float* p1 = x1 + ch * 4096 + g4 * 1024 + c;
    const float* p2 = x2 + ch * 4096 + g4 * 1024 + c;
#pragma unroll
    for (int j = 0; j < 8; ++j){ vA1[j] = p1[j * 128]; vA2[j] = p2[j * 128]; }
  };
  auto loadB = [&](int ch){
    const float* p1 = x1 + ch * 4096 + g4 * 1024 + c;
    const float* p2 = x2 + ch * 4096 + g4 * 1024 + c;
#pragma unroll
    for (int j = 0; j < 8; ++j){ vB1[j] = p1[j * 128]; vB2[j] = p2[j * 128]; }
  };
  auto writeA = [&](int buf){
    unsigned ah[4], al[4], bh[4], bl[4];
#pragma unroll
    for (int jj = 0; jj < 4; ++jj){
      uint2 p = hilo2(vA1[2*jj], vA1[2*jj+1]); ah[jj] = p.x; al[jj] = p.y;
      uint2 q = hilo2(vA2[2*jj], vA2[2*jj+1]); bh[jj] = q.x; bl[jj] = q.y;
    }
#pragma unroll
    for (int j = 0; j < 8; ++j){ s1a += vA1[j]; s2a += vA2[j]; }
    char* basew = lds + buf * 32768;
    *reinterpret_cast<uint4*>(basew         + offst) = make_uint4(ah[0],ah[1],ah[2],ah[3]);
    *reinterpret_cast<uint4*>(basew +  8192 + offst) = make_uint4(al[0],al[1],al[2],al[3]);
    *reinterpret_cast<uint4*>(basew + 16384 + offst) = make_uint4(bh[0],bh[1],bh[2],bh[3]);
    *reinterpret_cast<uint4*>(basew + 24576 + offst) = make_uint4(bl[0],bl[1],bl[2],bl[3]);
  };
  auto writeB = [&](int buf){
    unsigned ah[4], al[4], bh[4], bl[4];
#pragma unroll
    for (int jj = 0; jj < 4; ++jj){
      uint2 p = hilo2(vB1[2*jj], vB1[2*jj+1]); ah[jj] = p.x; al[jj] = p.y;
      uint2 q = hilo2(vB2[2*jj], vB2[2*jj+1]); bh[jj] = q.x; bl[jj] = q.y;
    }
#pragma unroll
    for (int j = 0; j < 8; ++j){ s1a += vB1[j]; s2a += vB2[j]; }
    char* basew = lds + buf * 32768;
    *reinterpret_cast<uint4*>(basew         + offst) = make_uint4(ah[0],ah[1],ah[2],ah[3]);
    *reinterpret_cast<uint4*>(basew +  8192 + offst) = make_uint4(al[0],al[1],al[2],al[3]);
    *reinterpret_cast<uint4*>(basew + 16384 + offst) = make_uint4(bh[0],bh[1],bh[2],bh[3]);
    *reinterpret_cast<uint4*>(basew + 24576 + offst) = make_uint4(bl[0],bl[1],bl[2],bl[3]);
  };
  auto mfma_buf = [&](const char* base){
    s16x8 a1h[2], a1l[2], a2h[2];
#pragma unroll
    for (int ri = 0; ri < 2; ++ri){
      a1h[ri] = lds_frag(base,         2*wr+ri, lane);
      a1l[ri] = lds_frag(base +  8192, 2*wr+ri, lane);
      a2h[ri] = lds_frag(base + 16384, 2*wr+ri, lane);
    }
#pragma unroll
    for (int ci = 0; ci < 4; ++ci){
      s16x8 b1h = lds_frag(base,         4*wc+ci, lane);
      s16x8 b2h = lds_frag(base + 16384, 4*wc+ci, lane);
      s16x8 b2l = lds_frag(base + 24576, 4*wc+ci, lane);
#pragma unroll
      for (int ri = 0; ri < 2; ++ri){
        acc[0][ri][ci] = __builtin_amdgcn_mfma_f32_16x16x32_bf16(a1h[ri], b1h, acc[0][ri][ci], 0, 0, 0);
        acc[2][ri][ci] = __builtin_amdgcn_mfma_f32_16x16x32_bf16(a2h[ri], b2h, acc[2][ri][ci], 0, 0, 0);
        acc[1][ri][ci] = __builtin_amdgcn_mfma_f32_16x16x32_bf16(a1h[ri], b2h, acc[1][ri][ci], 0, 0, 0);
        acc[1][ri][ci] = __builtin_amdgcn_mfma_f32_16x16x32_bf16(a1h[ri], b2l, acc[1][ri][ci], 0, 0, 0);
        acc[1][ri][ci] = __builtin_amdgcn_mfma_f32_16x16x32_bf16(a1l[ri], b2h, acc[1][ri][ci], 0, 0, 0);
      }
    }
  };

  // prologue: chunk b -> buf0 (via vB), then prefetch b+NB (vA), b+2NB (vB)
  loadB(b);
  writeB(0);
  if (b + NB     < NCHUNK) loadA(b + NB);
  if (b + 2 * NB < NCHUNK) loadB(b + 2 * NB);

  for (int ch = b; ch < NCHUNK; ch += 2 * NB){
    block_sync_lds();
    mfma_buf(lds);
    if (ch + NB     < NCHUNK) writeA(1);
    if (ch + 3 * NB < NCHUNK) loadA(ch + 3 * NB);
    const int ch2 = ch + NB;
    if (ch2 < NCHUNK){
      block_sync_lds();
      mfma_buf(lds + 32768);
      if (ch2 + NB     < NCHUNK) writeB(0);
      if (ch2 + 3 * NB < NCHUNK) loadB(ch2 + 3 * NB);
    }
  }

  const int gbase = b * GRAM_FLOATS;
  const int rr = (lane >> 4) * 4;
  const int cl = lane & 15;
#pragma unroll
  for (int m3 = 0; m3 < 3; ++m3)
#pragma unroll
    for (int ri = 0; ri < 2; ++ri)
#pragma unroll
      for (int ci = 0; ci < 4; ++ci)
#pragma unroll
        for (int r = 0; r < 4; ++r)
          partG[gbase + m3 * 16384 + (wr * 32 + ri * 16 + rr + r) * 128 + wc * 64 + ci * 16 + cl] = acc[m3][ri][ci][r];

  __syncthreads();
  float* sred = reinterpret_cast<float*>(lds);
  sred[t] = s1a; sred[512 + t] = s2a;
  __syncthreads();
  if (t < 128){
    partS[b * 256 + t] = sred[t] + sred[t + 128] + sred[t + 256] + sred[t + 384];
  } else if (t < 256){
    int j = t - 128;
    partS[b * 256 + 128 + j] = sred[512 + j] + sred[512 + j + 128] + sred[512 + j + 256] + sred[512 + j + 384];
  }
}

// ---------------- reduce partials, stage A: NB -> RSEG, float4, coalesced ----------------
__global__ void k_reduceA(const float* __restrict__ partG, float* __restrict__ part2, int NB)
{
  const int seg = blockIdx.x / 48;
  const int i4  = (blockIdx.x % 48) * 256 + threadIdx.x;   // 0..12287
  const int per = (NB + RSEG - 1) / RSEG;
  int b0 = seg * per;
  int b1 = b0 + per; if (b1 > NB) b1 = NB;
  f32x4 s = {0.f, 0.f, 0.f, 0.f};
  const f32x4* p = reinterpret_cast<const f32x4*>(partG) + i4;
  int b = b0;
  for (; b + 4 <= b1; b += 4){
    f32x4 v0 = p[(long)(b    ) * GRAM_F4];
    f32x4 v1 = p[(long)(b + 1) * GRAM_F4];
    f32x4 v2 = p[(long)(b + 2) * GRAM_F4];
    f32x4 v3 = p[(long)(b + 3) * GRAM_F4];
    s += (v0 + v1) + (v2 + v3);
  }
  for (; b < b1; ++b) s += p[(long)b * GRAM_F4];
  reinterpret_cast<f32x4*>(part2)[(long)seg * GRAM_F4 + i4] = s;
}

// ---------------- reduce partials, stage B: RSEG -> 1 (+ partS) ----------------
__global__ void k_reduceB(const float* __restrict__ part2, const float* __restrict__ partS,
                          float* __restrict__ G, float* __restrict__ sv, int NB)
{
  int idx = blockIdx.x * 256 + threadIdx.x;
  if (idx < GRAM_F4){
    f32x4 s = {0.f, 0.f, 0.f, 0.f};
    const f32x4* p = reinterpret_cast<const f32x4*>(part2) + idx;
#pragma unroll
    for (int g = 0; g < RSEG; ++g) s += p[(long)g * GRAM_F4];
    reinterpret_cast<f32x4*>(G)[idx] = s;
  } else if (idx < GRAM_F4 + 256){
    int j = idx - GRAM_F4;
    float s = 0.f;
#pragma unroll 8
    for (int b = 0; b < NB; ++b) s += partS[b * 256 + j];
    sv[j] = s;
  }
}

// ---------------- fused: S row i = Wq_i G12 Wk' + biases, softmax -> attn ----------------
__global__ void k_attnS(const float* __restrict__ G12, const float* __restrict__ Wq,
                        const float* __restrict__ Wk, const float* __restrict__ sv,
                        const float* __restrict__ bq, const float* __restrict__ bk,
                        float* __restrict__ attn)
{
  __shared__ float WqL[128], s2L[128], tj[128], red[128];
  const int i = blockIdx.x, o = threadIdx.x;
  float wqo = Wq[i * 128 + o];
  WqL[o] = wqo;
  s2L[o] = sv[128 + o];
  red[o] = wqo * sv[o];                 // u1_i partial
  __syncthreads();
  for (int st = 64; st; st >>= 1){ if (o < st) red[o] += red[o + st]; __syncthreads(); }
  float u1i = red[0];
  // t[j] = Wq_i . G12[:,j]
  float t = 0.f;
  for (int m = 0; m < 128; ++m) t += WqL[m] * G12[m * 128 + o];
  tj[o] = t;
  __syncthreads();
  // s[o] = t . Wk_o ; u2[o] = s2 . Wk_o
  float s = 0.f, u2o = 0.f;
  for (int j = 0; j < 128; ++j){
    float wkj = Wk[o * 128 + j];
    s   += tj[j]  * wkj;
    u2o += s2L[j] * wkj;
  }
  float bqi = bq[i], bko = bk[o];
  s += u1i * bko + bqi * u2o + 524288.0f * bqi * bko;
  // softmax over o
  red[o] = s; __syncthreads();
  for (int st = 64; st; st >>= 1){ if (o < st) red[o] = fmaxf(red[o], red[o + st]); __syncthreads(); }
  float mx = red[0]; __syncthreads();
  float e = expf(s - mx);
  red[o] = e; __syncthreads();
  for (int st = 64; st; st >>= 1){ if (o < st) red[o] += red[o + st]; __syncthreads(); }
  attn[i * 128 + o] = e / red[0];
}

// ---------------- fused: M column + BN stats -> A''(transposed bf16), c'' ----------------
__global__ void k_stats2(const float* __restrict__ attn, const float* __restrict__ G,
                         const float* __restrict__ sv, const float* __restrict__ Wq,
                         const float* __restrict__ Wk, const float* __restrict__ bq,
                         const float* __restrict__ bk, const float* __restrict__ bv1,
                         const float* __restrict__ bv2, const float* __restrict__ Wv1,
                         const float* __restrict__ Wv2, const float* __restrict__ gamma,
                         const float* __restrict__ beta,
                         unsigned short* __restrict__ AhT, float* __restrict__ cc)
{
  __shared__ float WvL[128], MoL[128], aL[128], red[128];
  int blk = blockIdx.x, tid = threadIdx.x;
  int ts = blk >> 7, o = blk & 127;
  const float* Gx  = G + (ts ? 2 * 16384 : 0);   // G11 or G22
  const float* sx  = sv + ts * 128;
  const float* W   = ts ? Wk : Wq;
  const float* bx  = ts ? bk : bq;
  const float* bvx = ts ? bv2 : bv1;
  const float* Wv  = ts ? Wv2 : Wv1;

  WvL[tid] = Wv[o * 128 + tid];
  __syncthreads();
  // M[k,o] = attn row k . Wv row o
  float mo = 0.f;
  for (int j = 0; j < 128; ++j) mo += attn[tid * 128 + j] * WvL[j];
  MoL[tid] = mo;
  __syncthreads();

  float a = (tid == o) ? 1.0f : 0.0f;   // column o of A = I + W' M
  float co = 0.f;
  for (int k = 0; k < 128; ++k){
    float mk = MoL[k];
    a  += W[k * 128 + tid] * mk;
    co += bx[k] * mk;
  }
  co += bvx[o];
  aL[tid] = a; __syncthreads();
  float ti = 0.f;
  for (int j = 0; j < 128; ++j) ti += Gx[tid * 128 + j] * aL[j];
  red[tid] = a * ti; __syncthreads();
  for (int st = 64; st; st >>= 1){ if (tid < st) red[tid] += red[tid + st]; __syncthreads(); }
  float quad = red[0]; __syncthreads();
  red[tid] = sx[tid] * a; __syncthreads();
  for (int st = 64; st; st >>= 1){ if (tid < st) red[tid] += red[tid + st]; __syncthreads(); }
  float sa = red[0];

  const float Bf = 524288.0f;
  float mu  = sa / Bf + co;
  float msq = quad / Bf + 2.f * co * sa / Bf + co * co;
  float var = msq - mu * mu;
  float gsc = gamma[o] * rsqrtf(var + 1e-5f);
  AhT[ts * 16384 + o * 128 + tid] = (unsigned short)bf16rn(a * gsc);
  if (tid == 0) cc[ts * 128 + o] = co * gsc + (beta[o] - mu * gsc);
}

// ---------------- pass 3: y = x @ A'' + c'' ----------------
// 256 thr = 4 waves; wave handles 16 rows x 128 cols; x single-bf16 (hi only).
// A''ᵀ staged once per block into XOR-swizzled LDS; MFMA operands SWAPPED
// (A-op = A''ᵀ frag, B-op = x frag) so D maps lane&15 -> y-row, regs -> 4
// consecutive y-cols => contiguous float4 stores.
__global__ __launch_bounds__(256) void k_apply(const float* __restrict__ x1,
                                               const float* __restrict__ x2,
                                               const unsigned short* __restrict__ AhT,
                                               const float* __restrict__ cc,
                                               float* __restrict__ out)
{
  __shared__ __align__(16) char smem[32768];
  const int tid = threadIdx.x;
  const int lane = tid & 63;
  const int w = tid >> 6;
  const int b = blockIdx.x;
  const int m = lane & 15;
  const int g = lane >> 4;
  const f32x4 zero4 = {0.f, 0.f, 0.f, 0.f};

  const int ts = (b >> 1) & 1;
  const float* x = ts ? x2 : x1;
  float* y = out + (long)ts * 67108864;

  // stage A''ᵀ (128 rows x 256B) swizzled: byte = r*256 + ((q*16) ^ ((r&7)<<4))
  const unsigned short* Ah = AhT + ts * 16384;
#pragma unroll
  for (int i = 0; i < 8; ++i){
    int u = i * 256 + tid;              // 16B unit 0..2047
    int r = u >> 4, q = u & 15;
    uint4 v = *reinterpret_cast<const uint4*>(Ah + u * 8);
    *reinterpret_cast<uint4*>(smem + r * 256 + ((q * 16) ^ ((r & 7) << 4))) = v;
  }
  f32x4 ccv4[8];
#pragma unroll
  for (int n = 0; n < 8; ++n)
    ccv4[n] = *reinterpret_cast<const f32x4*>(cc + ts * 128 + n * 16 + g * 4);
  __syncthreads();

  const int idx0 = (b >> 2) * 2 + (b & 1);
  const unsigned sw = (unsigned)((m & 7) << 4);

  for (int kj = 0; kj < 8; ++kj){
    const int rb = 8191 - (idx0 + kj * 1024);   // descending rows, both tensors in step
    const int r0w = rb * 64 + w * 16;
    const float* xp = x + (long)(r0w + m) * 128 + g * 8;

    s16x8 xh[4];
#pragma unroll
    for (int kc = 0; kc < 4; ++kc){
      float4 xa = *reinterpret_cast<const float4*>(xp + kc * 32);
      float4 xb = *reinterpret_cast<const float4*>(xp + kc * 32 + 4);
      unsigned p0 = bf16rn(xa.x) | (bf16rn(xa.y) << 16);
      unsigned p1 = bf16rn(xa.z) | (bf16rn(xa.w) << 16);
      unsigned p2 = bf16rn(xb.x) | (bf16rn(xb.y) << 16);
      unsigned p3 = bf16rn(xb.z) | (bf16rn(xb.w) << 16);
      xh[kc] = u4_frag(make_uint4(p0, p1, p2, p3));
    }

    f32x4 acc[8];
#pragma unroll
    for (int n = 0; n < 8; ++n) acc[n] = zero4;
#pragma unroll
    for (int n = 0; n < 8; ++n){
      const char* rp = smem + (n * 16 + m) * 256;
      s16x8 B0 = *reinterpret_cast<const s16x8*>(rp + ((0 * 64 + g * 16) ^ sw));
      s16x8 B1 = *reinterpret_cast<const s16x8*>(rp + ((1 * 64 + g * 16) ^ sw));
      s16x8 B2 = *reinterpret_cast<const s16x8*>(rp + ((2 * 64 + g * 16) ^ sw));
      s16x8 B3 = *reinterpret_cast<const s16x8*>(rp + ((3 * 64 + g * 16) ^ sw));
      acc[n] = __builtin_amdgcn_mfma_f32_16x16x32_bf16(B0, xh[0], acc[n], 0, 0, 0);
      acc[n] = __builtin_amdgcn_mfma_f32_16x16x32_bf16(B1, xh[1], acc[n], 0, 0, 0);
      acc[n] = __builtin_amdgcn_mfma_f32_16x16x32_bf16(B2, xh[2], acc[n], 0, 0, 0);
      acc[n] = __builtin_amdgcn_mfma_f32_16x16x32_bf16(B3, xh[3], acc[n], 0, 0, 0);
    }
    // D mapping after swap: y-row = r0w + m, y-cols = n*16 + g*4 + (0..3)
    float* yr = y + (long)(r0w + m) * 128 + g * 4;
#pragma unroll
    for (int n = 0; n < 8; ++n){
      f32x4 v = acc[n] + ccv4[n];
      *reinterpret_cast<f32x4*>(yr + n * 16) = v;
    }
  }
}

extern "C" void kernel_launch(void* const* d_in, const int* in_sizes, int n_in,
                              void* d_out, int out_size, void* d_ws, size_t ws_size,
                              hipStream_t stream)
{
  const float* x1  = (const float*)d_in[0];
  const float* x2  = (const float*)d_in[1];
  const float* Wq  = (const float*)d_in[2];
  const float* bq  = (const float*)d_in[3];
  const float* Wk  = (const float*)d_in[4];
  const float* bk  = (const float*)d_in[5];
  const float* Wv1 = (const float*)d_in[6];
  const float* bv1 = (const float*)d_in[7];
  const float* Wv2 = (const float*)d_in[8];
  const float* bv2 = (const float*)d_in[9];
  const float* gm  = (const float*)d_in[10];
  const float* bt  = (const float*)d_in[11];
  float* out = (float*)d_out;
  float* ws  = (float*)d_ws;

  long wsf = (long)(ws_size / 4);
  int NB = (int)((wsf - 500000) / 49408);   // per-block partials: 3*16384 + 256 floats
  if (NB > 256) NB = 256;
  if (NB < 1) NB = 1;

  float* partG = ws;                              // NB * 49152
  float* partS = partG + (long)NB * 49152;        // NB * 256
  float* part2 = partS + (long)NB * 256;          // RSEG * 49152 = 393216
  float* G     = part2 + (long)RSEG * GRAM_FLOATS;// G11 | G12 | G22
  float* sv    = G + 49152;                       // s1 | s2
  float* attn  = sv + 256;                        // 16384
  unsigned short* AhT = (unsigned short*)(attn + 16384);  // A1''ᵀ | A2''ᵀ as bf16
  float* cc    = (float*)(AhT + 32768);           // c1'' | c2''

  k_gram   <<<NB,       512, 0, stream>>>(x1, x2, partG, partS, NB);
  k_reduceA<<<RSEG*48,  256, 0, stream>>>(partG, part2, NB);
  k_reduceB<<<49,       256, 0, stream>>>(part2, partS, G, sv, NB);
  k_attnS  <<<128,      128, 0, stream>>>(G + 16384, Wq, Wk, sv, bq, bk, attn);
  k_stats2 <<<256,      128, 0, stream>>>(attn, G, sv, Wq, Wk, bq, bk, bv1, bv2, Wv1, Wv2, gm, bt, AhT, cc);
  k_apply  <<<2048,     256, 0, stream>>>(x1, x2, AhT, cc, out);
}

// Round 6
// 360.513 us; speedup vs baseline: 1.0001x; 1.0001x over previous
//
#include <hip/hip_runtime.h>

// FusionAttentionBlock: algebraic reduction.
//   G11=x1'x1, G12=x1'x2, G22=x2'x2, s1,s2 = colsums  (pass 1, MFMA bf16; G12 hi/lo split)
//   S = Wq G12 Wk' + (Wq s1) bk' + bq (Wk s2)' + B bq bk';  attn = softmax(S)
//   M = attn Wv', A = I + W' M, c = b@M + bv;  BN moments from G,s  ->  A'', c''
//   y = x @ A'' + c''                                        (pass 3, MFMA bf16 x-hi only)

#define NCHUNK 16384        // 524288 rows / 32 rows per chunk
#define GRAM_FLOATS 49152   // 3 * 128 * 128
#define GRAM_F4 12288
#define RSEG 8

typedef __attribute__((ext_vector_type(4))) float f32x4;
typedef __attribute__((ext_vector_type(8))) short s16x8;

__device__ __forceinline__ unsigned bf16rn(float f){
  unsigned x = __float_as_uint(f);
  return (x + 0x7FFFu + ((x >> 16) & 1u)) >> 16;
}

// two floats -> packed bf16-hi word and bf16-lo (residual) word
__device__ __forceinline__ uint2 hilo2(float a, float b){
  unsigned ha = bf16rn(a), hb = bf16rn(b);
  float la = a - __uint_as_float(ha << 16);
  float lb = b - __uint_as_float(hb << 16);
  return make_uint2(ha | (hb << 16), bf16rn(la) | (bf16rn(lb) << 16));
}

__device__ __forceinline__ s16x8 u4_frag(uint4 v){
  union { uint4 u; s16x8 s; } cv; cv.u = v; return cv.s;
}

// LDS per array: [128 cols][32 rows bf16 = 64B]; 16B chunks XOR-swizzled so both
// the column-major staging writes and the frag reads tile banks.
__device__ __forceinline__ unsigned lds_off(int c, int g){
  return (unsigned)(c * 64 + ((g ^ ((c >> 1) & 3)) << 4));
}

__device__ __forceinline__ s16x8 lds_frag(const char* base, int tile, int lane){
  int c = tile * 16 + (lane & 15);
  int g = lane >> 4;
  return *reinterpret_cast<const s16x8*>(base + lds_off(c, g));
}

// ---------------- pass 1: partial Gram matrices ----------------
// 512 thr = 8 waves in a 4x2 grid; wave owns 32 rows x 64 cols of each Gram.
__global__ __launch_bounds__(512) void k_gram(const float* __restrict__ x1,
                                              const float* __restrict__ x2,
                                              float* __restrict__ partG,
                                              float* __restrict__ partS,
                                              int NB)
{
  __shared__ __align__(16) char lds[65536];   // 2 buffers x 4 arrays x 8KB
  const int t    = threadIdx.x;
  const int lane = t & 63;
  const int w    = t >> 6;
  const int wr   = w >> 1;     // wave row 0..3  (rows wr*32..wr*32+31)
  const int wc   = w & 1;      // wave col 0..1  (cols wc*64..wc*64+63)
  const int c    = t & 127;    // staging column (feature)
  const int g4   = t >> 7;     // staging row-group (rows g4*8..g4*8+7)
  const int b    = blockIdx.x;

  const f32x4 zero4 = {0.f, 0.f, 0.f, 0.f};
  f32x4 acc[3][2][4];
#pragma unroll
  for (int m3 = 0; m3 < 3; ++m3)
#pragma unroll
    for (int ri = 0; ri < 2; ++ri)
#pragma unroll
      for (int ci = 0; ci < 4; ++ci) acc[m3][ri][ci] = zero4;

  float s1a = 0.f, s2a = 0.f;
  float vA1[8], vA2[8], vB1[8], vB2[8];

  const unsigned offst = lds_off(c, g4);

  auto loadA = [&](int ch){
    const float* p1 = x1 + ch * 4096 + g4 * 1024 + c;
    const float* p2 = x2 + ch * 4096 + g4 * 1024 + c;
#pragma unroll
    for (int j = 0; j < 8; ++j){ vA1[j] = p1[j * 128]; vA2[j] = p2[j * 128]; }
  };
  auto loadB = [&](int ch){
    const float* p1 = x1 + ch * 4096 + g4 * 1024 + c;
    const float* p2 = x2 + ch * 4096 + g4 * 1024 + c;
#pragma unroll
    for (int j = 0; j < 8; ++j){ vB1[j] = p1[j * 128]; vB2[j] = p2[j * 128]; }
  };
  auto writeA = [&](int buf){
    unsigned ah[4], al[4], bh[4], bl[4];
#pragma unroll
    for (int jj = 0; jj < 4; ++jj){
      uint2 p = hilo2(vA1[2*jj], vA1[2*jj+1]); ah[jj] = p.x; al[jj] = p.y;
      uint2 q = hilo2(vA2[2*jj], vA2[2*jj+1]); bh[jj] = q.x; bl[jj] = q.y;
    }
#pragma unroll
    for (int j = 0; j < 8; ++j){ s1a += vA1[j]; s2a += vA2[j]; }
    char* basew = lds + buf * 32768;
    *reinterpret_cast<uint4*>(basew         + offst) = make_uint4(ah[0],ah[1],ah[2],ah[3]);
    *reinterpret_cast<uint4*>(basew +  8192 + offst) = make_uint4(al[0],al[1],al[2],al[3]);
    *reinterpret_cast<uint4*>(basew + 16384 + offst) = make_uint4(bh[0],bh[1],bh[2],bh[3]);
    *reinterpret_cast<uint4*>(basew + 24576 + offst) = make_uint4(bl[0],bl[1],bl[2],bl[3]);
  };
  auto writeB = [&](int buf){
    unsigned ah[4], al[4], bh[4], bl[4];
#pragma unroll
    for (int jj = 0; jj < 4; ++jj){
      uint2 p = hilo2(vB1[2*jj], vB1[2*jj+1]); ah[jj] = p.x; al[jj] = p.y;
      uint2 q = hilo2(vB2[2*jj], vB2[2*jj+1]); bh[jj] = q.x; bl[jj] = q.y;
    }
#pragma unroll
    for (int j = 0; j < 8; ++j){ s1a += vB1[j]; s2a += vB2[j]; }
    char* basew = lds + buf * 32768;
    *reinterpret_cast<uint4*>(basew         + offst) = make_uint4(ah[0],ah[1],ah[2],ah[3]);
    *reinterpret_cast<uint4*>(basew +  8192 + offst) = make_uint4(al[0],al[1],al[2],al[3]);
    *reinterpret_cast<uint4*>(basew + 16384 + offst) = make_uint4(bh[0],bh[1],bh[2],bh[3]);
    *reinterpret_cast<uint4*>(basew + 24576 + offst) = make_uint4(bl[0],bl[1],bl[2],bl[3]);
  };
  auto mfma_buf = [&](const char* base){
    s16x8 a1h[2], a1l[2], a2h[2];
#pragma unroll
    for (int ri = 0; ri < 2; ++ri){
      a1h[ri] = lds_frag(base,         2*wr+ri, lane);
      a1l[ri] = lds_frag(base +  8192, 2*wr+ri, lane);
      a2h[ri] = lds_frag(base + 16384, 2*wr+ri, lane);
    }
#pragma unroll
    for (int ci = 0; ci < 4; ++ci){
      s16x8 b1h = lds_frag(base,         4*wc+ci, lane);
      s16x8 b2h = lds_frag(base + 16384, 4*wc+ci, lane);
      s16x8 b2l = lds_frag(base + 24576, 4*wc+ci, lane);
#pragma unroll
      for (int ri = 0; ri < 2; ++ri){
        acc[0][ri][ci] = __builtin_amdgcn_mfma_f32_16x16x32_bf16(a1h[ri], b1h, acc[0][ri][ci], 0, 0, 0);
        acc[2][ri][ci] = __builtin_amdgcn_mfma_f32_16x16x32_bf16(a2h[ri], b2h, acc[2][ri][ci], 0, 0, 0);
        acc[1][ri][ci] = __builtin_amdgcn_mfma_f32_16x16x32_bf16(a1h[ri], b2h, acc[1][ri][ci], 0, 0, 0);
        acc[1][ri][ci] = __builtin_amdgcn_mfma_f32_16x16x32_bf16(a1h[ri], b2l, acc[1][ri][ci], 0, 0, 0);
        acc[1][ri][ci] = __builtin_amdgcn_mfma_f32_16x16x32_bf16(a1l[ri], b2h, acc[1][ri][ci], 0, 0, 0);
      }
    }
  };

  // prologue: chunk b -> buf0 (via vB), then prefetch b+NB (vA), b+2NB (vB)
  loadB(b);
  writeB(0);
  if (b + NB     < NCHUNK) loadA(b + NB);
  if (b + 2 * NB < NCHUNK) loadB(b + 2 * NB);

  for (int ch = b; ch < NCHUNK; ch += 2 * NB){
    __syncthreads();
    mfma_buf(lds);
    if (ch + NB     < NCHUNK) writeA(1);
    if (ch + 3 * NB < NCHUNK) loadA(ch + 3 * NB);
    const int ch2 = ch + NB;
    if (ch2 < NCHUNK){
      __syncthreads();
      mfma_buf(lds + 32768);
      if (ch2 + NB     < NCHUNK) writeB(0);
      if (ch2 + 3 * NB < NCHUNK) loadB(ch2 + 3 * NB);
    }
  }

  const int gbase = b * GRAM_FLOATS;
  const int rr = (lane >> 4) * 4;
  const int cl = lane & 15;
#pragma unroll
  for (int m3 = 0; m3 < 3; ++m3)
#pragma unroll
    for (int ri = 0; ri < 2; ++ri)
#pragma unroll
      for (int ci = 0; ci < 4; ++ci)
#pragma unroll
        for (int r = 0; r < 4; ++r)
          partG[gbase + m3 * 16384 + (wr * 32 + ri * 16 + rr + r) * 128 + wc * 64 + ci * 16 + cl] = acc[m3][ri][ci][r];

  __syncthreads();
  float* sred = reinterpret_cast<float*>(lds);
  sred[t] = s1a; sred[512 + t] = s2a;
  __syncthreads();
  if (t < 128){
    partS[b * 256 + t] = sred[t] + sred[t + 128] + sred[t + 256] + sred[t + 384];
  } else if (t < 256){
    int j = t - 128;
    partS[b * 256 + 128 + j] = sred[512 + j] + sred[512 + j + 128] + sred[512 + j + 256] + sred[512 + j + 384];
  }
}

// ---------------- reduce partials, stage A: NB -> RSEG, float4, coalesced ----------------
__global__ void k_reduceA(const float* __restrict__ partG, float* __restrict__ part2, int NB)
{
  const int seg = blockIdx.x / 48;
  const int i4  = (blockIdx.x % 48) * 256 + threadIdx.x;   // 0..12287
  const int per = (NB + RSEG - 1) / RSEG;
  int b0 = seg * per;
  int b1 = b0 + per; if (b1 > NB) b1 = NB;
  f32x4 s = {0.f, 0.f, 0.f, 0.f};
  const f32x4* p = reinterpret_cast<const f32x4*>(partG) + i4;
  int b = b0;
  for (; b + 4 <= b1; b += 4){
    f32x4 v0 = p[(long)(b    ) * GRAM_F4];
    f32x4 v1 = p[(long)(b + 1) * GRAM_F4];
    f32x4 v2 = p[(long)(b + 2) * GRAM_F4];
    f32x4 v3 = p[(long)(b + 3) * GRAM_F4];
    s += (v0 + v1) + (v2 + v3);
  }
  for (; b < b1; ++b) s += p[(long)b * GRAM_F4];
  reinterpret_cast<f32x4*>(part2)[(long)seg * GRAM_F4 + i4] = s;
}

// ---------------- reduce partials, stage B: RSEG -> 1 (+ partS) ----------------
__global__ void k_reduceB(const float* __restrict__ part2, const float* __restrict__ partS,
                          float* __restrict__ G, float* __restrict__ sv, int NB)
{
  int idx = blockIdx.x * 256 + threadIdx.x;
  if (idx < GRAM_F4){
    f32x4 s = {0.f, 0.f, 0.f, 0.f};
    const f32x4* p = reinterpret_cast<const f32x4*>(part2) + idx;
#pragma unroll
    for (int g = 0; g < RSEG; ++g) s += p[(long)g * GRAM_F4];
    reinterpret_cast<f32x4*>(G)[idx] = s;
  } else if (idx < GRAM_F4 + 256){
    int j = idx - GRAM_F4;
    float s = 0.f;
#pragma unroll 8
    for (int b = 0; b < NB; ++b) s += partS[b * 256 + j];
    sv[j] = s;
  }
}

// ---------------- fused: S row i = Wq_i G12 Wk' + biases, softmax -> attn ----------------
__global__ void k_attnS(const float* __restrict__ G12, const float* __restrict__ Wq,
                        const float* __restrict__ Wk, const float* __restrict__ sv,
                        const float* __restrict__ bq, const float* __restrict__ bk,
                        float* __restrict__ attn)
{
  __shared__ float WqL[128], s2L[128], tj[128], red[128];
  const int i = blockIdx.x, o = threadIdx.x;
  float wqo = Wq[i * 128 + o];
  WqL[o] = wqo;
  s2L[o] = sv[128 + o];
  red[o] = wqo * sv[o];                 // u1_i partial
  __syncthreads();
  for (int st = 64; st; st >>= 1){ if (o < st) red[o] += red[o + st]; __syncthreads(); }
  float u1i = red[0];
  // t[j] = Wq_i . G12[:,j]
  float t = 0.f;
  for (int m = 0; m < 128; ++m) t += WqL[m] * G12[m * 128 + o];
  tj[o] = t;
  __syncthreads();
  // s[o] = t . Wk_o ; u2[o] = s2 . Wk_o
  float s = 0.f, u2o = 0.f;
  for (int j = 0; j < 128; ++j){
    float wkj = Wk[o * 128 + j];
    s   += tj[j]  * wkj;
    u2o += s2L[j] * wkj;
  }
  float bqi = bq[i], bko = bk[o];
  s += u1i * bko + bqi * u2o + 524288.0f * bqi * bko;
  // softmax over o
  red[o] = s; __syncthreads();
  for (int st = 64; st; st >>= 1){ if (o < st) red[o] = fmaxf(red[o], red[o + st]); __syncthreads(); }
  float mx = red[0]; __syncthreads();
  float e = expf(s - mx);
  red[o] = e; __syncthreads();
  for (int st = 64; st; st >>= 1){ if (o < st) red[o] += red[o + st]; __syncthreads(); }
  attn[i * 128 + o] = e / red[0];
}

// ---------------- fused: M column + BN stats -> A''(transposed bf16), c'' ----------------
__global__ void k_stats2(const float* __restrict__ attn, const float* __restrict__ G,
                         const float* __restrict__ sv, const float* __restrict__ Wq,
                         const float* __restrict__ Wk, const float* __restrict__ bq,
                         const float* __restrict__ bk, const float* __restrict__ bv1,
                         const float* __restrict__ bv2, const float* __restrict__ Wv1,
                         const float* __restrict__ Wv2, const float* __restrict__ gamma,
                         const float* __restrict__ beta,
                         unsigned short* __restrict__ AhT, float* __restrict__ cc)
{
  __shared__ float WvL[128], MoL[128], aL[128], red[128];
  int blk = blockIdx.x, tid = threadIdx.x;
  int ts = blk >> 7, o = blk & 127;
  const float* Gx  = G + (ts ? 2 * 16384 : 0);   // G11 or G22
  const float* sx  = sv + ts * 128;
  const float* W   = ts ? Wk : Wq;
  const float* bx  = ts ? bk : bq;
  const float* bvx = ts ? bv2 : bv1;
  const float* Wv  = ts ? Wv2 : Wv1;

  WvL[tid] = Wv[o * 128 + tid];
  __syncthreads();
  // M[k,o] = attn row k . Wv row o
  float mo = 0.f;
  for (int j = 0; j < 128; ++j) mo += attn[tid * 128 + j] * WvL[j];
  MoL[tid] = mo;
  __syncthreads();

  float a = (tid == o) ? 1.0f : 0.0f;   // column o of A = I + W' M
  float co = 0.f;
  for (int k = 0; k < 128; ++k){
    float mk = MoL[k];
    a  += W[k * 128 + tid] * mk;
    co += bx[k] * mk;
  }
  co += bvx[o];
  aL[tid] = a; __syncthreads();
  float ti = 0.f;
  for (int j = 0; j < 128; ++j) ti += Gx[tid * 128 + j] * aL[j];
  red[tid] = a * ti; __syncthreads();
  for (int st = 64; st; st >>= 1){ if (tid < st) red[tid] += red[tid + st]; __syncthreads(); }
  float quad = red[0]; __syncthreads();
  red[tid] = sx[tid] * a; __syncthreads();
  for (int st = 64; st; st >>= 1){ if (tid < st) red[tid] += red[tid + st]; __syncthreads(); }
  float sa = red[0];

  const float Bf = 524288.0f;
  float mu  = sa / Bf + co;
  float msq = quad / Bf + 2.f * co * sa / Bf + co * co;
  float var = msq - mu * mu;
  float gsc = gamma[o] * rsqrtf(var + 1e-5f);
  AhT[ts * 16384 + o * 128 + tid] = (unsigned short)bf16rn(a * gsc);
  if (tid == 0) cc[ts * 128 + o] = co * gsc + (beta[o] - mu * gsc);
}

// ---------------- pass 3: y = x @ A'' + c'' ----------------
// 256 thr = 4 waves; wave handles 16 rows x 128 cols; x single-bf16 (hi only).
// A''ᵀ staged once per block into XOR-swizzled LDS; MFMA operands SWAPPED
// (A-op = A''ᵀ frag, B-op = x frag) => D maps lane&15 -> y-row, regs -> 4
// consecutive y-cols => contiguous float4 stores (nontemporal: y is write-once).
// One-job-ahead register prefetch of x hides HBM latency under MFMA+stores.
__global__ __launch_bounds__(256) void k_apply(const float* __restrict__ x1,
                                               const float* __restrict__ x2,
                                               const unsigned short* __restrict__ AhT,
                                               const float* __restrict__ cc,
                                               float* __restrict__ out)
{
  __shared__ __align__(16) char smem[32768];
  const int tid = threadIdx.x;
  const int lane = tid & 63;
  const int w = tid >> 6;
  const int b = blockIdx.x;
  const int m = lane & 15;
  const int g = lane >> 4;
  const f32x4 zero4 = {0.f, 0.f, 0.f, 0.f};

  const int ts = (b >> 1) & 1;
  const float* x = ts ? x2 : x1;
  float* y = out + (long)ts * 67108864;

  // stage A''ᵀ (128 rows x 256B) swizzled: byte = r*256 + ((q*16) ^ ((r&7)<<4))
  const unsigned short* Ah = AhT + ts * 16384;
#pragma unroll
  for (int i = 0; i < 8; ++i){
    int u = i * 256 + tid;              // 16B unit 0..2047
    int r = u >> 4, q = u & 15;
    uint4 v = *reinterpret_cast<const uint4*>(Ah + u * 8);
    *reinterpret_cast<uint4*>(smem + r * 256 + ((q * 16) ^ ((r & 7) << 4))) = v;
  }
  f32x4 ccv4[8];
#pragma unroll
  for (int n = 0; n < 8; ++n)
    ccv4[n] = *reinterpret_cast<const f32x4*>(cc + ts * 128 + n * 16 + g * 4);
  __syncthreads();

  const int idx0 = (b >> 2) * 2 + (b & 1);
  const unsigned sw = (unsigned)((m & 7) << 4);

  auto jobp = [&](int kj){
    const int rb = 8191 - (idx0 + kj * 1024);   // descending rows, x1/x2 in step
    return x + (long)(rb * 64 + w * 16 + m) * 128 + g * 8;
  };

  float4 pf[8];
  {
    const float* xp = jobp(0);
#pragma unroll
    for (int kc = 0; kc < 4; ++kc){
      pf[2*kc]   = *reinterpret_cast<const float4*>(xp + kc * 32);
      pf[2*kc+1] = *reinterpret_cast<const float4*>(xp + kc * 32 + 4);
    }
  }

#pragma unroll
  for (int kj = 0; kj < 8; ++kj){
    float4 cur[8];
#pragma unroll
    for (int q = 0; q < 8; ++q) cur[q] = pf[q];
    if (kj < 7){
      const float* xp = jobp(kj + 1);
#pragma unroll
      for (int kc = 0; kc < 4; ++kc){
        pf[2*kc]   = *reinterpret_cast<const float4*>(xp + kc * 32);
        pf[2*kc+1] = *reinterpret_cast<const float4*>(xp + kc * 32 + 4);
      }
    }

    s16x8 xh[4];
#pragma unroll
    for (int kc = 0; kc < 4; ++kc){
      float4 xa = cur[2*kc], xb = cur[2*kc+1];
      unsigned p0 = bf16rn(xa.x) | (bf16rn(xa.y) << 16);
      unsigned p1 = bf16rn(xa.z) | (bf16rn(xa.w) << 16);
      unsigned p2 = bf16rn(xb.x) | (bf16rn(xb.y) << 16);
      unsigned p3 = bf16rn(xb.z) | (bf16rn(xb.w) << 16);
      xh[kc] = u4_frag(make_uint4(p0, p1, p2, p3));
    }

    f32x4 acc[8];
#pragma unroll
    for (int n = 0; n < 8; ++n) acc[n] = zero4;
#pragma unroll
    for (int n = 0; n < 8; ++n){
      const char* rp = smem + (n * 16 + m) * 256;
      s16x8 B0 = *reinterpret_cast<const s16x8*>(rp + ((0 * 64 + g * 16) ^ sw));
      s16x8 B1 = *reinterpret_cast<const s16x8*>(rp + ((1 * 64 + g * 16) ^ sw));
      s16x8 B2 = *reinterpret_cast<const s16x8*>(rp + ((2 * 64 + g * 16) ^ sw));
      s16x8 B3 = *reinterpret_cast<const s16x8*>(rp + ((3 * 64 + g * 16) ^ sw));
      acc[n] = __builtin_amdgcn_mfma_f32_16x16x32_bf16(B0, xh[0], acc[n], 0, 0, 0);
      acc[n] = __builtin_amdgcn_mfma_f32_16x16x32_bf16(B1, xh[1], acc[n], 0, 0, 0);
      acc[n] = __builtin_amdgcn_mfma_f32_16x16x32_bf16(B2, xh[2], acc[n], 0, 0, 0);
      acc[n] = __builtin_amdgcn_mfma_f32_16x16x32_bf16(B3, xh[3], acc[n], 0, 0, 0);
    }
    // D mapping after swap: y-row = r0w + m, y-cols = n*16 + g*4 + (0..3)
    const int rb = 8191 - (idx0 + kj * 1024);
    float* yr = y + (long)(rb * 64 + w * 16 + m) * 128 + g * 4;
#pragma unroll
    for (int n = 0; n < 8; ++n){
      f32x4 v = acc[n] + ccv4[n];
      __builtin_nontemporal_store(v, reinterpret_cast<f32x4*>(yr + n * 16));
    }
  }
}

extern "C" void kernel_launch(void* const* d_in, const int* in_sizes, int n_in,
                              void* d_out, int out_size, void* d_ws, size_t ws_size,
                              hipStream_t stream)
{
  const float* x1  = (const float*)d_in[0];
  const float* x2  = (const float*)d_in[1];
  const float* Wq  = (const float*)d_in[2];
  const float* bq  = (const float*)d_in[3];
  const float* Wk  = (const float*)d_in[4];
  const float* bk  = (const float*)d_in[5];
  const float* Wv1 = (const float*)d_in[6];
  const float* bv1 = (const float*)d_in[7];
  const float* Wv2 = (const float*)d_in[8];
  const float* bv2 = (const float*)d_in[9];
  const float* gm  = (const float*)d_in[10];
  const float* bt  = (const float*)d_in[11];
  float* out = (float*)d_out;
  float* ws  = (float*)d_ws;

  long wsf = (long)(ws_size / 4);
  int NB = (int)((wsf - 500000) / 49408);   // per-block partials: 3*16384 + 256 floats
  if (NB > 256) NB = 256;
  if (NB < 1) NB = 1;

  float* partG = ws;                              // NB * 49152
  float* partS = partG + (long)NB * 49152;        // NB * 256
  float* part2 = partS + (long)NB * 256;          // RSEG * 49152 = 393216
  float* G     = part2 + (long)RSEG * GRAM_FLOATS;// G11 | G12 | G22
  float* sv    = G + 49152;                       // s1 | s2
  float* attn  = sv + 256;                        // 16384
  unsigned short* AhT = (unsigned short*)(attn + 16384);  // A1''ᵀ | A2''ᵀ as bf16
  float* cc    = (float*)(AhT + 32768);           // c1'' | c2''

  k_gram   <<<NB,       512, 0, stream>>>(x1, x2, partG, partS, NB);
  k_reduceA<<<RSEG*48,  256, 0, stream>>>(partG, part2, NB);
  k_reduceB<<<49,       256, 0, stream>>>(part2, partS, G, sv, NB);
  k_attnS  <<<128,      128, 0, stream>>>(G + 16384, Wq, Wk, sv, bq, bk, attn);
  k_stats2 <<<256,      128, 0, stream>>>(attn, G, sv, Wq, Wk, bq, bk, bv1, bv2, Wv1, Wv2, gm, bt, AhT, cc);
  k_apply  <<<2048,     256, 0, stream>>>(x1, x2, AhT, cc, out);
}

// Round 7
// 351.584 us; speedup vs baseline: 1.0255x; 1.0254x over previous
//
#include <hip/hip_runtime.h>

// FusionAttentionBlock: algebraic reduction.
//   G11=x1'x1, G12=x1'x2, G22=x2'x2, s1,s2 = colsums  (pass 1, MFMA bf16; G12 hi/lo split)
//   S = Wq G12 Wk' + (Wq s1) bk' + bq (Wk s2)' + B bq bk';  attn = softmax(S)
//   M = attn Wv', A = I + W' M, c = b@M + bv;  BN moments from G,s  ->  A'', c''
//   y = x @ A'' + c''                                        (pass 3, MFMA bf16 x-hi only)

#define NCHUNK 16384        // 524288 rows / 32 rows per chunk
#define GRAM_FLOATS 49152   // 3 * 128 * 128
#define GRAM_F4 12288
#define RSEG 8

typedef __attribute__((ext_vector_type(4))) float f32x4;
typedef __attribute__((ext_vector_type(8))) short s16x8;

__device__ __forceinline__ unsigned bf16rn(float f){
  unsigned x = __float_as_uint(f);
  return (x + 0x7FFFu + ((x >> 16) & 1u)) >> 16;
}

// two floats -> packed bf16-hi word and bf16-lo (residual) word
__device__ __forceinline__ uint2 hilo2(float a, float b){
  unsigned ha = bf16rn(a), hb = bf16rn(b);
  float la = a - __uint_as_float(ha << 16);
  float lb = b - __uint_as_float(hb << 16);
  return make_uint2(ha | (hb << 16), bf16rn(la) | (bf16rn(lb) << 16));
}

__device__ __forceinline__ s16x8 u4_frag(uint4 v){
  union { uint4 u; s16x8 s; } cv; cv.u = v; return cv.s;
}

// LDS per array: [128 cols][32 rows bf16 = 64B]; 16B chunks XOR-swizzled so both
// the column-major staging writes and the frag reads tile banks.
__device__ __forceinline__ unsigned lds_off(int c, int g){
  return (unsigned)(c * 64 + ((g ^ ((c >> 1) & 3)) << 4));
}

__device__ __forceinline__ s16x8 lds_frag(const char* base, int tile, int lane){
  int c = tile * 16 + (lane & 15);
  int g = lane >> 4;
  return *reinterpret_cast<const s16x8*>(base + lds_off(c, g));
}

// ---------------- pass 1: partial Gram matrices ----------------
// 512 thr = 8 waves in a 4x2 grid; wave owns 32 rows x 64 cols of each Gram.
// T14 stage-split per sub-iteration: convert (consume staging regs) -> issue
// next global loads EARLY -> mfma -> ds_write. Loads are ~full MFMA phase old
// when __syncthreads' vmcnt(0) drain hits -> latency hidden.
__global__ __launch_bounds__(512) void k_gram(const float* __restrict__ x1,
                                              const float* __restrict__ x2,
                                              float* __restrict__ partG,
                                              float* __restrict__ partS,
                                              int NB)
{
  __shared__ __align__(16) char lds[65536];   // 2 buffers x 4 arrays x 8KB
  const int t    = threadIdx.x;
  const int lane = t & 63;
  const int w    = t >> 6;
  const int wr   = w >> 1;     // wave row 0..3  (rows wr*32..wr*32+31)
  const int wc   = w & 1;      // wave col 0..1  (cols wc*64..wc*64+63)
  const int c    = t & 127;    // staging column (feature)
  const int g4   = t >> 7;     // staging row-group (rows g4*8..g4*8+7)
  const int b    = blockIdx.x;

  const f32x4 zero4 = {0.f, 0.f, 0.f, 0.f};
  f32x4 acc[3][2][4];
#pragma unroll
  for (int m3 = 0; m3 < 3; ++m3)
#pragma unroll
    for (int ri = 0; ri < 2; ++ri)
#pragma unroll
      for (int ci = 0; ci < 4; ++ci) acc[m3][ri][ci] = zero4;

  float s1a = 0.f, s2a = 0.f;
  float vA1[8], vA2[8], vB1[8], vB2[8];
  unsigned pkA[16], pkB[16];

  const unsigned offst = lds_off(c, g4);

  auto loadA = [&](int ch){
    const float* p1 = x1 + ch * 4096 + g4 * 1024 + c;
    const float* p2 = x2 + ch * 4096 + g4 * 1024 + c;
#pragma unroll
    for (int j = 0; j < 8; ++j){ vA1[j] = p1[j * 128]; vA2[j] = p2[j * 128]; }
  };
  auto loadB = [&](int ch){
    const float* p1 = x1 + ch * 4096 + g4 * 1024 + c;
    const float* p2 = x2 + ch * 4096 + g4 * 1024 + c;
#pragma unroll
    for (int j = 0; j < 8; ++j){ vB1[j] = p1[j * 128]; vB2[j] = p2[j * 128]; }
  };
  auto convertA = [&](){
#pragma unroll
    for (int jj = 0; jj < 4; ++jj){
      uint2 p = hilo2(vA1[2*jj], vA1[2*jj+1]); pkA[jj] = p.x; pkA[4+jj] = p.y;
      uint2 q = hilo2(vA2[2*jj], vA2[2*jj+1]); pkA[8+jj] = q.x; pkA[12+jj] = q.y;
    }
#pragma unroll
    for (int j = 0; j < 8; ++j){ s1a += vA1[j]; s2a += vA2[j]; }
  };
  auto convertB = [&](){
#pragma unroll
    for (int jj = 0; jj < 4; ++jj){
      uint2 p = hilo2(vB1[2*jj], vB1[2*jj+1]); pkB[jj] = p.x; pkB[4+jj] = p.y;
      uint2 q = hilo2(vB2[2*jj], vB2[2*jj+1]); pkB[8+jj] = q.x; pkB[12+jj] = q.y;
    }
#pragma unroll
    for (int j = 0; j < 8; ++j){ s1a += vB1[j]; s2a += vB2[j]; }
  };
  auto dswriteA = [&](int buf){
    char* basew = lds + buf * 32768;
    *reinterpret_cast<uint4*>(basew         + offst) = make_uint4(pkA[0],pkA[1],pkA[2],pkA[3]);
    *reinterpret_cast<uint4*>(basew +  8192 + offst) = make_uint4(pkA[4],pkA[5],pkA[6],pkA[7]);
    *reinterpret_cast<uint4*>(basew + 16384 + offst) = make_uint4(pkA[8],pkA[9],pkA[10],pkA[11]);
    *reinterpret_cast<uint4*>(basew + 24576 + offst) = make_uint4(pkA[12],pkA[13],pkA[14],pkA[15]);
  };
  auto dswriteB = [&](int buf){
    char* basew = lds + buf * 32768;
    *reinterpret_cast<uint4*>(basew         + offst) = make_uint4(pkB[0],pkB[1],pkB[2],pkB[3]);
    *reinterpret_cast<uint4*>(basew +  8192 + offst) = make_uint4(pkB[4],pkB[5],pkB[6],pkB[7]);
    *reinterpret_cast<uint4*>(basew + 16384 + offst) = make_uint4(pkB[8],pkB[9],pkB[10],pkB[11]);
    *reinterpret_cast<uint4*>(basew + 24576 + offst) = make_uint4(pkB[12],pkB[13],pkB[14],pkB[15]);
  };
  auto mfma_buf = [&](const char* base){
    s16x8 a1h[2], a1l[2], a2h[2];
#pragma unroll
    for (int ri = 0; ri < 2; ++ri){
      a1h[ri] = lds_frag(base,         2*wr+ri, lane);
      a1l[ri] = lds_frag(base +  8192, 2*wr+ri, lane);
      a2h[ri] = lds_frag(base + 16384, 2*wr+ri, lane);
    }
#pragma unroll
    for (int ci = 0; ci < 4; ++ci){
      s16x8 b1h = lds_frag(base,         4*wc+ci, lane);
      s16x8 b2h = lds_frag(base + 16384, 4*wc+ci, lane);
      s16x8 b2l = lds_frag(base + 24576, 4*wc+ci, lane);
#pragma unroll
      for (int ri = 0; ri < 2; ++ri){
        acc[0][ri][ci] = __builtin_amdgcn_mfma_f32_16x16x32_bf16(a1h[ri], b1h, acc[0][ri][ci], 0, 0, 0);
        acc[2][ri][ci] = __builtin_amdgcn_mfma_f32_16x16x32_bf16(a2h[ri], b2h, acc[2][ri][ci], 0, 0, 0);
        acc[1][ri][ci] = __builtin_amdgcn_mfma_f32_16x16x32_bf16(a1h[ri], b2h, acc[1][ri][ci], 0, 0, 0);
        acc[1][ri][ci] = __builtin_amdgcn_mfma_f32_16x16x32_bf16(a1h[ri], b2l, acc[1][ri][ci], 0, 0, 0);
        acc[1][ri][ci] = __builtin_amdgcn_mfma_f32_16x16x32_bf16(a1l[ri], b2h, acc[1][ri][ci], 0, 0, 0);
      }
    }
  };

  // prologue: chunk b -> buf0 (via vB), then prefetch b+NB (vA), b+2NB (vB)
  loadB(b);
  convertB();
  dswriteB(0);
  if (b + NB     < NCHUNK) loadA(b + NB);
  if (b + 2 * NB < NCHUNK) loadB(b + 2 * NB);

  for (int ch = b; ch < NCHUNK; ch += 2 * NB){
    // sub 0: compute buf0; stage ch+NB (vA) -> buf1; issue ch+3NB -> vA
    __syncthreads();
    if (ch + NB     < NCHUNK) convertA();
    if (ch + 3 * NB < NCHUNK) loadA(ch + 3 * NB);
    mfma_buf(lds);
    if (ch + NB     < NCHUNK) dswriteA(1);
    const int ch2 = ch + NB;
    if (ch2 < NCHUNK){
      // sub 1: compute buf1; stage ch2+NB (vB) -> buf0; issue ch2+3NB -> vB
      __syncthreads();
      if (ch2 + NB     < NCHUNK) convertB();
      if (ch2 + 3 * NB < NCHUNK) loadB(ch2 + 3 * NB);
      mfma_buf(lds + 32768);
      if (ch2 + NB     < NCHUNK) dswriteB(0);
    }
  }

  const int gbase = b * GRAM_FLOATS;
  const int rr = (lane >> 4) * 4;
  const int cl = lane & 15;
#pragma unroll
  for (int m3 = 0; m3 < 3; ++m3)
#pragma unroll
    for (int ri = 0; ri < 2; ++ri)
#pragma unroll
      for (int ci = 0; ci < 4; ++ci)
#pragma unroll
        for (int r = 0; r < 4; ++r)
          partG[gbase + m3 * 16384 + (wr * 32 + ri * 16 + rr + r) * 128 + wc * 64 + ci * 16 + cl] = acc[m3][ri][ci][r];

  __syncthreads();
  float* sred = reinterpret_cast<float*>(lds);
  sred[t] = s1a; sred[512 + t] = s2a;
  __syncthreads();
  if (t < 128){
    partS[b * 256 + t] = sred[t] + sred[t + 128] + sred[t + 256] + sred[t + 384];
  } else if (t < 256){
    int j = t - 128;
    partS[b * 256 + 128 + j] = sred[512 + j] + sred[512 + j + 128] + sred[512 + j + 256] + sred[512 + j + 384];
  }
}

// ---------------- reduce partials, stage A: NB -> RSEG, float4, coalesced ----------------
__global__ void k_reduceA(const float* __restrict__ partG, float* __restrict__ part2, int NB)
{
  const int seg = blockIdx.x / 48;
  const int i4  = (blockIdx.x % 48) * 256 + threadIdx.x;   // 0..12287
  const int per = (NB + RSEG - 1) / RSEG;
  int b0 = seg * per;
  int b1 = b0 + per; if (b1 > NB) b1 = NB;
  f32x4 s = {0.f, 0.f, 0.f, 0.f};
  const f32x4* p = reinterpret_cast<const f32x4*>(partG) + i4;
  int b = b0;
  for (; b + 4 <= b1; b += 4){
    f32x4 v0 = p[(long)(b    ) * GRAM_F4];
    f32x4 v1 = p[(long)(b + 1) * GRAM_F4];
    f32x4 v2 = p[(long)(b + 2) * GRAM_F4];
    f32x4 v3 = p[(long)(b + 3) * GRAM_F4];
    s += (v0 + v1) + (v2 + v3);
  }
  for (; b < b1; ++b) s += p[(long)b * GRAM_F4];
  reinterpret_cast<f32x4*>(part2)[(long)seg * GRAM_F4 + i4] = s;
}

// ---------------- reduce partials, stage B: RSEG -> 1 (+ partS) ----------------
__global__ void k_reduceB(const float* __restrict__ part2, const float* __restrict__ partS,
                          float* __restrict__ G, float* __restrict__ sv, int NB)
{
  int idx = blockIdx.x * 256 + threadIdx.x;
  if (idx < GRAM_F4){
    f32x4 s = {0.f, 0.f, 0.f, 0.f};
    const f32x4* p = reinterpret_cast<const f32x4*>(part2) + idx;
#pragma unroll
    for (int g = 0; g < RSEG; ++g) s += p[(long)g * GRAM_F4];
    reinterpret_cast<f32x4*>(G)[idx] = s;
  } else if (idx < GRAM_F4 + 256){
    int j = idx - GRAM_F4;
    float s = 0.f;
#pragma unroll 8
    for (int b = 0; b < NB; ++b) s += partS[b * 256 + j];
    sv[j] = s;
  }
}

// ---------------- fused: S row i = Wq_i G12 Wk' + biases, softmax -> attn ----------------
__global__ void k_attnS(const float* __restrict__ G12, const float* __restrict__ Wq,
                        const float* __restrict__ Wk, const float* __restrict__ sv,
                        const float* __restrict__ bq, const float* __restrict__ bk,
                        float* __restrict__ attn)
{
  __shared__ float WqL[128], s2L[128], tj[128], red[128];
  const int i = blockIdx.x, o = threadIdx.x;
  float wqo = Wq[i * 128 + o];
  WqL[o] = wqo;
  s2L[o] = sv[128 + o];
  red[o] = wqo * sv[o];                 // u1_i partial
  __syncthreads();
  for (int st = 64; st; st >>= 1){ if (o < st) red[o] += red[o + st]; __syncthreads(); }
  float u1i = red[0];
  // t[j] = Wq_i . G12[:,j]
  float t = 0.f;
  for (int m = 0; m < 128; ++m) t += WqL[m] * G12[m * 128 + o];
  tj[o] = t;
  __syncthreads();
  // s[o] = t . Wk_o ; u2[o] = s2 . Wk_o
  float s = 0.f, u2o = 0.f;
  for (int j = 0; j < 128; ++j){
    float wkj = Wk[o * 128 + j];
    s   += tj[j]  * wkj;
    u2o += s2L[j] * wkj;
  }
  float bqi = bq[i], bko = bk[o];
  s += u1i * bko + bqi * u2o + 524288.0f * bqi * bko;
  // softmax over o
  red[o] = s; __syncthreads();
  for (int st = 64; st; st >>= 1){ if (o < st) red[o] = fmaxf(red[o], red[o + st]); __syncthreads(); }
  float mx = red[0]; __syncthreads();
  float e = expf(s - mx);
  red[o] = e; __syncthreads();
  for (int st = 64; st; st >>= 1){ if (o < st) red[o] += red[o + st]; __syncthreads(); }
  attn[i * 128 + o] = e / red[0];
}

// ---------------- fused: M column + BN stats -> A''(transposed bf16), c'' ----------------
__global__ void k_stats2(const float* __restrict__ attn, const float* __restrict__ G,
                         const float* __restrict__ sv, const float* __restrict__ Wq,
                         const float* __restrict__ Wk, const float* __restrict__ bq,
                         const float* __restrict__ bk, const float* __restrict__ bv1,
                         const float* __restrict__ bv2, const float* __restrict__ Wv1,
                         const float* __restrict__ Wv2, const float* __restrict__ gamma,
                         const float* __restrict__ beta,
                         unsigned short* __restrict__ AhT, float* __restrict__ cc)
{
  __shared__ float WvL[128], MoL[128], aL[128], red[128];
  int blk = blockIdx.x, tid = threadIdx.x;
  int ts = blk >> 7, o = blk & 127;
  const float* Gx  = G + (ts ? 2 * 16384 : 0);   // G11 or G22
  const float* sx  = sv + ts * 128;
  const float* W   = ts ? Wk : Wq;
  const float* bx  = ts ? bk : bq;
  const float* bvx = ts ? bv2 : bv1;
  const float* Wv  = ts ? Wv2 : Wv1;

  WvL[tid] = Wv[o * 128 + tid];
  __syncthreads();
  // M[k,o] = attn row k . Wv row o
  float mo = 0.f;
  for (int j = 0; j < 128; ++j) mo += attn[tid * 128 + j] * WvL[j];
  MoL[tid] = mo;
  __syncthreads();

  float a = (tid == o) ? 1.0f : 0.0f;   // column o of A = I + W' M
  float co = 0.f;
  for (int k = 0; k < 128; ++k){
    float mk = MoL[k];
    a  += W[k * 128 + tid] * mk;
    co += bx[k] * mk;
  }
  co += bvx[o];
  aL[tid] = a; __syncthreads();
  float ti = 0.f;
  for (int j = 0; j < 128; ++j) ti += Gx[tid * 128 + j] * aL[j];
  red[tid] = a * ti; __syncthreads();
  for (int st = 64; st; st >>= 1){ if (tid < st) red[tid] += red[tid + st]; __syncthreads(); }
  float quad = red[0]; __syncthreads();
  red[tid] = sx[tid] * a; __syncthreads();
  for (int st = 64; st; st >>= 1){ if (tid < st) red[tid] += red[tid + st]; __syncthreads(); }
  float sa = red[0];

  const float Bf = 524288.0f;
  float mu  = sa / Bf + co;
  float msq = quad / Bf + 2.f * co * sa / Bf + co * co;
  float var = msq - mu * mu;
  float gsc = gamma[o] * rsqrtf(var + 1e-5f);
  AhT[ts * 16384 + o * 128 + tid] = (unsigned short)bf16rn(a * gsc);
  if (tid == 0) cc[ts * 128 + o] = co * gsc + (beta[o] - mu * gsc);
}

// ---------------- pass 3: y = x @ A'' + c'' ----------------
// 256 thr = 4 waves; wave handles 16 rows x 128 cols; x single-bf16 (hi only).
// A''ᵀ staged once per block into XOR-swizzled LDS (32 KB); frags read per job.
// Job order: descending row blocks, x1/x2 interleaved (L3 tail reuse).
// (R4-proven variant: unswapped operands, scalar stores.)
__global__ __launch_bounds__(256) void k_apply(const float* __restrict__ x1,
                                               const float* __restrict__ x2,
                                               const unsigned short* __restrict__ AhT,
                                               const float* __restrict__ cc,
                                               float* __restrict__ out)
{
  __shared__ __align__(16) char smem[32768];
  const int tid = threadIdx.x;
  const int lane = tid & 63;
  const int w = tid >> 6;
  const int b = blockIdx.x;
  const int m = lane & 15;
  const int g = lane >> 4;
  const f32x4 zero4 = {0.f, 0.f, 0.f, 0.f};

  const int ts = (b >> 1) & 1;
  const float* x = ts ? x2 : x1;
  float* y = out + (long)ts * 67108864;

  // stage A''ᵀ (128 rows x 256B) swizzled: byte = r*256 + ((q*16) ^ ((r&7)<<4))
  const unsigned short* Ah = AhT + ts * 16384;
#pragma unroll
  for (int i = 0; i < 8; ++i){
    int u = i * 256 + tid;              // 16B unit 0..2047
    int r = u >> 4, q = u & 15;
    uint4 v = *reinterpret_cast<const uint4*>(Ah + u * 8);
    *reinterpret_cast<uint4*>(smem + r * 256 + ((q * 16) ^ ((r & 7) << 4))) = v;
  }
  float ccv[8];
#pragma unroll
  for (int n = 0; n < 8; ++n) ccv[n] = cc[ts * 128 + n * 16 + m];
  __syncthreads();

  const int idx0 = (b >> 2) * 2 + (b & 1);
  const unsigned sw = (unsigned)((m & 7) << 4);

  for (int kj = 0; kj < 8; ++kj){
    const int rb = 8191 - (idx0 + kj * 1024);   // descending rows, both tensors in step
    const int r0w = rb * 64 + w * 16;
    const float* xp = x + (long)(r0w + m) * 128 + g * 8;

    s16x8 xh[4];
#pragma unroll
    for (int kc = 0; kc < 4; ++kc){
      float4 xa = *reinterpret_cast<const float4*>(xp + kc * 32);
      float4 xb = *reinterpret_cast<const float4*>(xp + kc * 32 + 4);
      unsigned p0 = bf16rn(xa.x) | (bf16rn(xa.y) << 16);
      unsigned p1 = bf16rn(xa.z) | (bf16rn(xa.w) << 16);
      unsigned p2 = bf16rn(xb.x) | (bf16rn(xb.y) << 16);
      unsigned p3 = bf16rn(xb.z) | (bf16rn(xb.w) << 16);
      xh[kc] = u4_frag(make_uint4(p0, p1, p2, p3));
    }

    f32x4 acc[8];
#pragma unroll
    for (int n = 0; n < 8; ++n) acc[n] = zero4;
#pragma unroll
    for (int n = 0; n < 8; ++n){
      const char* rp = smem + (n * 16 + m) * 256;
      s16x8 B0 = *reinterpret_cast<const s16x8*>(rp + ((0 * 64 + g * 16) ^ sw));
      s16x8 B1 = *reinterpret_cast<const s16x8*>(rp + ((1 * 64 + g * 16) ^ sw));
      s16x8 B2 = *reinterpret_cast<const s16x8*>(rp + ((2 * 64 + g * 16) ^ sw));
      s16x8 B3 = *reinterpret_cast<const s16x8*>(rp + ((3 * 64 + g * 16) ^ sw));
      acc[n] = __builtin_amdgcn_mfma_f32_16x16x32_bf16(xh[0], B0, acc[n], 0, 0, 0);
      acc[n] = __builtin_amdgcn_mfma_f32_16x16x32_bf16(xh[1], B1, acc[n], 0, 0, 0);
      acc[n] = __builtin_amdgcn_mfma_f32_16x16x32_bf16(xh[2], B2, acc[n], 0, 0, 0);
      acc[n] = __builtin_amdgcn_mfma_f32_16x16x32_bf16(xh[3], B3, acc[n], 0, 0, 0);
    }
#pragma unroll
    for (int n = 0; n < 8; ++n)
#pragma unroll
      for (int r = 0; r < 4; ++r)
        y[(long)(r0w + g * 4 + r) * 128 + n * 16 + m] = acc[n][r] + ccv[n];
  }
}

extern "C" void kernel_launch(void* const* d_in, const int* in_sizes, int n_in,
                              void* d_out, int out_size, void* d_ws, size_t ws_size,
                              hipStream_t stream)
{
  const float* x1  = (const float*)d_in[0];
  const float* x2  = (const float*)d_in[1];
  const float* Wq  = (const float*)d_in[2];
  const float* bq  = (const float*)d_in[3];
  const float* Wk  = (const float*)d_in[4];
  const float* bk  = (const float*)d_in[5];
  const float* Wv1 = (const float*)d_in[6];
  const float* bv1 = (const float*)d_in[7];
  const float* Wv2 = (const float*)d_in[8];
  const float* bv2 = (const float*)d_in[9];
  const float* gm  = (const float*)d_in[10];
  const float* bt  = (const float*)d_in[11];
  float* out = (float*)d_out;
  float* ws  = (float*)d_ws;

  long wsf = (long)(ws_size / 4);
  int NB = (int)((wsf - 500000) / 49408);   // per-block partials: 3*16384 + 256 floats
  if (NB > 256) NB = 256;
  if (NB < 1) NB = 1;

  float* partG = ws;                              // NB * 49152
  float* partS = partG + (long)NB * 49152;        // NB * 256
  float* part2 = partS + (long)NB * 256;          // RSEG * 49152 = 393216
  float* G     = part2 + (long)RSEG * GRAM_FLOATS;// G11 | G12 | G22
  float* sv    = G + 49152;                       // s1 | s2
  float* attn  = sv + 256;                        // 16384
  unsigned short* AhT = (unsigned short*)(attn + 16384);  // A1''ᵀ | A2''ᵀ as bf16
  float* cc    = (float*)(AhT + 32768);           // c1'' | c2''

  k_gram   <<<NB,       512, 0, stream>>>(x1, x2, partG, partS, NB);
  k_reduceA<<<RSEG*48,  256, 0, stream>>>(partG, part2, NB);
  k_reduceB<<<49,       256, 0, stream>>>(part2, partS, G, sv, NB);
  k_attnS  <<<128,      128, 0, stream>>>(G + 16384, Wq, Wk, sv, bq, bk, attn);
  k_stats2 <<<256,      128, 0, stream>>>(attn, G, sv, Wq, Wk, bq, bk, bv1, bv2, Wv1, Wv2, gm, bt, AhT, cc);
  k_apply  <<<2048,     256, 0, stream>>>(x1, x2, AhT, cc, out);
}

// Round 8
// 342.938 us; speedup vs baseline: 1.0513x; 1.0252x over previous
//
#include <hip/hip_runtime.h>

// FusionAttentionBlock: algebraic reduction.
//   G11=x1'x1, G12=x1'x2, G22=x2'x2, s1,s2 = colsums  (pass 1, MFMA bf16; G12 hi/lo split)
//   S = Wq G12 Wk' + (Wq s1) bk' + bq (Wk s2)' + B bq bk';  attn = softmax(S)
//   M = attn Wv', A = I + W' M, c = b@M + bv;  BN moments from G,s  ->  A'', c''
//   y = x @ A'' + c''                                        (pass 3, MFMA bf16 x-hi only)

#define NCHUNK 16384        // 524288 rows / 32 rows per chunk
#define GRAM_FLOATS 49152   // 3 * 128 * 128
#define GRAM_F4 12288
#define RSEG 8

typedef __attribute__((ext_vector_type(4))) float f32x4;
typedef __attribute__((ext_vector_type(8))) short s16x8;

__device__ __forceinline__ unsigned bf16rn(float f){
  unsigned x = __float_as_uint(f);
  return (x + 0x7FFFu + ((x >> 16) & 1u)) >> 16;
}

// two floats -> packed bf16-hi word and bf16-lo (residual) word
__device__ __forceinline__ uint2 hilo2(float a, float b){
  unsigned ha = bf16rn(a), hb = bf16rn(b);
  float la = a - __uint_as_float(ha << 16);
  float lb = b - __uint_as_float(hb << 16);
  return make_uint2(ha | (hb << 16), bf16rn(la) | (bf16rn(lb) << 16));
}

__device__ __forceinline__ s16x8 u4_frag(uint4 v){
  union { uint4 u; s16x8 s; } cv; cv.u = v; return cv.s;
}

// LDS per array: [128 cols][32 rows bf16 = 64B]; 16B chunks XOR-swizzled so both
// the column-major staging writes and the frag reads tile banks.
__device__ __forceinline__ unsigned lds_off(int c, int g){
  return (unsigned)(c * 64 + ((g ^ ((c >> 1) & 3)) << 4));
}

__device__ __forceinline__ s16x8 lds_frag(const char* base, int tile, int lane){
  int c = tile * 16 + (lane & 15);
  int g = lane >> 4;
  return *reinterpret_cast<const s16x8*>(base + lds_off(c, g));
}

// ---------------- pass 1: partial Gram matrices ----------------
// 512 thr = 8 waves in a 4x2 grid; wave owns 32 rows x 64 cols of each Gram.
// (R4-proven structure: mfma -> stage -> load-issue, plain __syncthreads.)
__global__ __launch_bounds__(512) void k_gram(const float* __restrict__ x1,
                                              const float* __restrict__ x2,
                                              float* __restrict__ partG,
                                              float* __restrict__ partS,
                                              int NB)
{
  __shared__ __align__(16) char lds[65536];   // 2 buffers x 4 arrays x 8KB
  const int t    = threadIdx.x;
  const int lane = t & 63;
  const int w    = t >> 6;
  const int wr   = w >> 1;     // wave row 0..3  (rows wr*32..wr*32+31)
  const int wc   = w & 1;      // wave col 0..1  (cols wc*64..wc*64+63)
  const int c    = t & 127;    // staging column (feature)
  const int g4   = t >> 7;     // staging row-group (rows g4*8..g4*8+7)
  const int b    = blockIdx.x;

  const f32x4 zero4 = {0.f, 0.f, 0.f, 0.f};
  f32x4 acc[3][2][4];
#pragma unroll
  for (int m3 = 0; m3 < 3; ++m3)
#pragma unroll
    for (int ri = 0; ri < 2; ++ri)
#pragma unroll
      for (int ci = 0; ci < 4; ++ci) acc[m3][ri][ci] = zero4;

  float s1a = 0.f, s2a = 0.f;
  float vA1[8], vA2[8], vB1[8], vB2[8];

  const unsigned offst = lds_off(c, g4);

  auto loadA = [&](int ch){
    const float* p1 = x1 + ch * 4096 + g4 * 1024 + c;
    const float* p2 = x2 + ch * 4096 + g4 * 1024 + c;
#pragma unroll
    for (int j = 0; j < 8; ++j){ vA1[j] = p1[j * 128]; vA2[j] = p2[j * 128]; }
  };
  auto loadB = [&](int ch){
    const float* p1 = x1 + ch * 4096 + g4 * 1024 + c;
    const float* p2 = x2 + ch * 4096 + g4 * 1024 + c;
#pragma unroll
    for (int j = 0; j < 8; ++j){ vB1[j] = p1[j * 128]; vB2[j] = p2[j * 128]; }
  };
  auto writeA = [&](int buf){
    unsigned ah[4], al[4], bh[4], bl[4];
#pragma unroll
    for (int jj = 0; jj < 4; ++jj){
      uint2 p = hilo2(vA1[2*jj], vA1[2*jj+1]); ah[jj] = p.x; al[jj] = p.y;
      uint2 q = hilo2(vA2[2*jj], vA2[2*jj+1]); bh[jj] = q.x; bl[jj] = q.y;
    }
#pragma unroll
    for (int j = 0; j < 8; ++j){ s1a += vA1[j]; s2a += vA2[j]; }
    char* basew = lds + buf * 32768;
    *reinterpret_cast<uint4*>(basew         + offst) = make_uint4(ah[0],ah[1],ah[2],ah[3]);
    *reinterpret_cast<uint4*>(basew +  8192 + offst) = make_uint4(al[0],al[1],al[2],al[3]);
    *reinterpret_cast<uint4*>(basew + 16384 + offst) = make_uint4(bh[0],bh[1],bh[2],bh[3]);
    *reinterpret_cast<uint4*>(basew + 24576 + offst) = make_uint4(bl[0],bl[1],bl[2],bl[3]);
  };
  auto writeB = [&](int buf){
    unsigned ah[4], al[4], bh[4], bl[4];
#pragma unroll
    for (int jj = 0; jj < 4; ++jj){
      uint2 p = hilo2(vB1[2*jj], vB1[2*jj+1]); ah[jj] = p.x; al[jj] = p.y;
      uint2 q = hilo2(vB2[2*jj], vB2[2*jj+1]); bh[jj] = q.x; bl[jj] = q.y;
    }
#pragma unroll
    for (int j = 0; j < 8; ++j){ s1a += vB1[j]; s2a += vB2[j]; }
    char* basew = lds + buf * 32768;
    *reinterpret_cast<uint4*>(basew         + offst) = make_uint4(ah[0],ah[1],ah[2],ah[3]);
    *reinterpret_cast<uint4*>(basew +  8192 + offst) = make_uint4(al[0],al[1],al[2],al[3]);
    *reinterpret_cast<uint4*>(basew + 16384 + offst) = make_uint4(bh[0],bh[1],bh[2],bh[3]);
    *reinterpret_cast<uint4*>(basew + 24576 + offst) = make_uint4(bl[0],bl[1],bl[2],bl[3]);
  };
  auto mfma_buf = [&](const char* base){
    s16x8 a1h[2], a1l[2], a2h[2];
#pragma unroll
    for (int ri = 0; ri < 2; ++ri){
      a1h[ri] = lds_frag(base,         2*wr+ri, lane);
      a1l[ri] = lds_frag(base +  8192, 2*wr+ri, lane);
      a2h[ri] = lds_frag(base + 16384, 2*wr+ri, lane);
    }
#pragma unroll
    for (int ci = 0; ci < 4; ++ci){
      s16x8 b1h = lds_frag(base,         4*wc+ci, lane);
      s16x8 b2h = lds_frag(base + 16384, 4*wc+ci, lane);
      s16x8 b2l = lds_frag(base + 24576, 4*wc+ci, lane);
#pragma unroll
      for (int ri = 0; ri < 2; ++ri){
        acc[0][ri][ci] = __builtin_amdgcn_mfma_f32_16x16x32_bf16(a1h[ri], b1h, acc[0][ri][ci], 0, 0, 0);
        acc[2][ri][ci] = __builtin_amdgcn_mfma_f32_16x16x32_bf16(a2h[ri], b2h, acc[2][ri][ci], 0, 0, 0);
        acc[1][ri][ci] = __builtin_amdgcn_mfma_f32_16x16x32_bf16(a1h[ri], b2h, acc[1][ri][ci], 0, 0, 0);
        acc[1][ri][ci] = __builtin_amdgcn_mfma_f32_16x16x32_bf16(a1h[ri], b2l, acc[1][ri][ci], 0, 0, 0);
        acc[1][ri][ci] = __builtin_amdgcn_mfma_f32_16x16x32_bf16(a1l[ri], b2h, acc[1][ri][ci], 0, 0, 0);
      }
    }
  };

  // prologue: chunk b -> buf0 (via vB), then prefetch b+NB (vA), b+2NB (vB)
  loadB(b);
  writeB(0);
  if (b + NB     < NCHUNK) loadA(b + NB);
  if (b + 2 * NB < NCHUNK) loadB(b + 2 * NB);

  for (int ch = b; ch < NCHUNK; ch += 2 * NB){
    __syncthreads();
    mfma_buf(lds);
    if (ch + NB     < NCHUNK) writeA(1);
    if (ch + 3 * NB < NCHUNK) loadA(ch + 3 * NB);
    const int ch2 = ch + NB;
    if (ch2 < NCHUNK){
      __syncthreads();
      mfma_buf(lds + 32768);
      if (ch2 + NB     < NCHUNK) writeB(0);
      if (ch2 + 3 * NB < NCHUNK) loadB(ch2 + 3 * NB);
    }
  }

  const int gbase = b * GRAM_FLOATS;
  const int rr = (lane >> 4) * 4;
  const int cl = lane & 15;
#pragma unroll
  for (int m3 = 0; m3 < 3; ++m3)
#pragma unroll
    for (int ri = 0; ri < 2; ++ri)
#pragma unroll
      for (int ci = 0; ci < 4; ++ci)
#pragma unroll
        for (int r = 0; r < 4; ++r)
          partG[gbase + m3 * 16384 + (wr * 32 + ri * 16 + rr + r) * 128 + wc * 64 + ci * 16 + cl] = acc[m3][ri][ci][r];

  __syncthreads();
  float* sred = reinterpret_cast<float*>(lds);
  sred[t] = s1a; sred[512 + t] = s2a;
  __syncthreads();
  if (t < 128){
    partS[b * 256 + t] = sred[t] + sred[t + 128] + sred[t + 256] + sred[t + 384];
  } else if (t < 256){
    int j = t - 128;
    partS[b * 256 + 128 + j] = sred[512 + j] + sred[512 + j + 128] + sred[512 + j + 256] + sred[512 + j + 384];
  }
}

// ---------------- reduce partials, stage A: NB -> RSEG, float4, coalesced ----------------
__global__ void k_reduceA(const float* __restrict__ partG, float* __restrict__ part2, int NB)
{
  const int seg = blockIdx.x / 48;
  const int i4  = (blockIdx.x % 48) * 256 + threadIdx.x;   // 0..12287
  const int per = (NB + RSEG - 1) / RSEG;
  int b0 = seg * per;
  int b1 = b0 + per; if (b1 > NB) b1 = NB;
  f32x4 s = {0.f, 0.f, 0.f, 0.f};
  const f32x4* p = reinterpret_cast<const f32x4*>(partG) + i4;
  int b = b0;
  for (; b + 4 <= b1; b += 4){
    f32x4 v0 = p[(long)(b    ) * GRAM_F4];
    f32x4 v1 = p[(long)(b + 1) * GRAM_F4];
    f32x4 v2 = p[(long)(b + 2) * GRAM_F4];
    f32x4 v3 = p[(long)(b + 3) * GRAM_F4];
    s += (v0 + v1) + (v2 + v3);
  }
  for (; b < b1; ++b) s += p[(long)b * GRAM_F4];
  reinterpret_cast<f32x4*>(part2)[(long)seg * GRAM_F4 + i4] = s;
}

// ---------------- reduce partials, stage B: RSEG -> 1 (+ partS) ----------------
__global__ void k_reduceB(const float* __restrict__ part2, const float* __restrict__ partS,
                          float* __restrict__ G, float* __restrict__ sv, int NB)
{
  int idx = blockIdx.x * 256 + threadIdx.x;
  if (idx < GRAM_F4){
    f32x4 s = {0.f, 0.f, 0.f, 0.f};
    const f32x4* p = reinterpret_cast<const f32x4*>(part2) + idx;
#pragma unroll
    for (int g = 0; g < RSEG; ++g) s += p[(long)g * GRAM_F4];
    reinterpret_cast<f32x4*>(G)[idx] = s;
  } else if (idx < GRAM_F4 + 256){
    int j = idx - GRAM_F4;
    float s = 0.f;
#pragma unroll 8
    for (int b = 0; b < NB; ++b) s += partS[b * 256 + j];
    sv[j] = s;
  }
}

// ---------------- fused: S row i = Wq_i G12 Wk' + biases, softmax -> attn ----------------
__global__ void k_attnS(const float* __restrict__ G12, const float* __restrict__ Wq,
                        const float* __restrict__ Wk, const float* __restrict__ sv,
                        const float* __restrict__ bq, const float* __restrict__ bk,
                        float* __restrict__ attn)
{
  __shared__ float WqL[128], s2L[128], tj[128], red[128];
  const int i = blockIdx.x, o = threadIdx.x;
  float wqo = Wq[i * 128 + o];
  WqL[o] = wqo;
  s2L[o] = sv[128 + o];
  red[o] = wqo * sv[o];                 // u1_i partial
  __syncthreads();
  for (int st = 64; st; st >>= 1){ if (o < st) red[o] += red[o + st]; __syncthreads(); }
  float u1i = red[0];
  // t[j] = Wq_i . G12[:,j]
  float t = 0.f;
  for (int m = 0; m < 128; ++m) t += WqL[m] * G12[m * 128 + o];
  tj[o] = t;
  __syncthreads();
  // s[o] = t . Wk_o ; u2[o] = s2 . Wk_o
  float s = 0.f, u2o = 0.f;
  for (int j = 0; j < 128; ++j){
    float wkj = Wk[o * 128 + j];
    s   += tj[j]  * wkj;
    u2o += s2L[j] * wkj;
  }
  float bqi = bq[i], bko = bk[o];
  s += u1i * bko + bqi * u2o + 524288.0f * bqi * bko;
  // softmax over o
  red[o] = s; __syncthreads();
  for (int st = 64; st; st >>= 1){ if (o < st) red[o] = fmaxf(red[o], red[o + st]); __syncthreads(); }
  float mx = red[0]; __syncthreads();
  float e = expf(s - mx);
  red[o] = e; __syncthreads();
  for (int st = 64; st; st >>= 1){ if (o < st) red[o] += red[o + st]; __syncthreads(); }
  attn[i * 128 + o] = e / red[0];
}

// ---------------- fused: M column + BN stats -> A''(transposed bf16), c'' ----------------
__global__ void k_stats2(const float* __restrict__ attn, const float* __restrict__ G,
                         const float* __restrict__ sv, const float* __restrict__ Wq,
                         const float* __restrict__ Wk, const float* __restrict__ bq,
                         const float* __restrict__ bk, const float* __restrict__ bv1,
                         const float* __restrict__ bv2, const float* __restrict__ Wv1,
                         const float* __restrict__ Wv2, const float* __restrict__ gamma,
                         const float* __restrict__ beta,
                         unsigned short* __restrict__ AhT, float* __restrict__ cc)
{
  __shared__ float WvL[128], MoL[128], aL[128], red[128];
  int blk = blockIdx.x, tid = threadIdx.x;
  int ts = blk >> 7, o = blk & 127;
  const float* Gx  = G + (ts ? 2 * 16384 : 0);   // G11 or G22
  const float* sx  = sv + ts * 128;
  const float* W   = ts ? Wk : Wq;
  const float* bx  = ts ? bk : bq;
  const float* bvx = ts ? bv2 : bv1;
  const float* Wv  = ts ? Wv2 : Wv1;

  WvL[tid] = Wv[o * 128 + tid];
  __syncthreads();
  // M[k,o] = attn row k . Wv row o
  float mo = 0.f;
  for (int j = 0; j < 128; ++j) mo += attn[tid * 128 + j] * WvL[j];
  MoL[tid] = mo;
  __syncthreads();

  float a = (tid == o) ? 1.0f : 0.0f;   // column o of A = I + W' M
  float co = 0.f;
  for (int k = 0; k < 128; ++k){
    float mk = MoL[k];
    a  += W[k * 128 + tid] * mk;
    co += bx[k] * mk;
  }
  co += bvx[o];
  aL[tid] = a; __syncthreads();
  float ti = 0.f;
  for (int j = 0; j < 128; ++j) ti += Gx[tid * 128 + j] * aL[j];
  red[tid] = a * ti; __syncthreads();
  for (int st = 64; st; st >>= 1){ if (tid < st) red[tid] += red[tid + st]; __syncthreads(); }
  float quad = red[0]; __syncthreads();
  red[tid] = sx[tid] * a; __syncthreads();
  for (int st = 64; st; st >>= 1){ if (tid < st) red[tid] += red[tid + st]; __syncthreads(); }
  float sa = red[0];

  const float Bf = 524288.0f;
  float mu  = sa / Bf + co;
  float msq = quad / Bf + 2.f * co * sa / Bf + co * co;
  float var = msq - mu * mu;
  float gsc = gamma[o] * rsqrtf(var + 1e-5f);
  AhT[ts * 16384 + o * 128 + tid] = (unsigned short)bf16rn(a * gsc);
  if (tid == 0) cc[ts * 128 + o] = co * gsc + (beta[o] - mu * gsc);
}

// ---------------- pass 3: y = x @ A'' + c'' ----------------
// 256 thr = 4 waves; wave handles 16 rows x 128 cols; x single-bf16 (hi only).
// A''ᵀ staged once per block into XOR-swizzled LDS (32 KB); frags read per job.
// Job order: descending row blocks, x1/x2 interleaved (L3 tail reuse).
// y stores NONTEMPORAL: keep the 512 MB write stream from evicting the
// L3-resident x tail that the descending order re-reads.
__global__ __launch_bounds__(256) void k_apply(const float* __restrict__ x1,
                                               const float* __restrict__ x2,
                                               const unsigned short* __restrict__ AhT,
                                               const float* __restrict__ cc,
                                               float* __restrict__ out)
{
  __shared__ __align__(16) char smem[32768];
  const int tid = threadIdx.x;
  const int lane = tid & 63;
  const int w = tid >> 6;
  const int b = blockIdx.x;
  const int m = lane & 15;
  const int g = lane >> 4;
  const f32x4 zero4 = {0.f, 0.f, 0.f, 0.f};

  const int ts = (b >> 1) & 1;
  const float* x = ts ? x2 : x1;
  float* y = out + (long)ts * 67108864;

  // stage A''ᵀ (128 rows x 256B) swizzled: byte = r*256 + ((q*16) ^ ((r&7)<<4))
  const unsigned short* Ah = AhT + ts * 16384;
#pragma unroll
  for (int i = 0; i < 8; ++i){
    int u = i * 256 + tid;              // 16B unit 0..2047
    int r = u >> 4, q = u & 15;
    uint4 v = *reinterpret_cast<const uint4*>(Ah + u * 8);
    *reinterpret_cast<uint4*>(smem + r * 256 + ((q * 16) ^ ((r & 7) << 4))) = v;
  }
  float ccv[8];
#pragma unroll
  for (int n = 0; n < 8; ++n) ccv[n] = cc[ts * 128 + n * 16 + m];
  __syncthreads();

  const int idx0 = (b >> 2) * 2 + (b & 1);
  const unsigned sw = (unsigned)((m & 7) << 4);

  for (int kj = 0; kj < 8; ++kj){
    const int rb = 8191 - (idx0 + kj * 1024);   // descending rows, both tensors in step
    const int r0w = rb * 64 + w * 16;
    const float* xp = x + (long)(r0w + m) * 128 + g * 8;

    s16x8 xh[4];
#pragma unroll
    for (int kc = 0; kc < 4; ++kc){
      float4 xa = *reinterpret_cast<const float4*>(xp + kc * 32);
      float4 xb = *reinterpret_cast<const float4*>(xp + kc * 32 + 4);
      unsigned p0 = bf16rn(xa.x) | (bf16rn(xa.y) << 16);
      unsigned p1 = bf16rn(xa.z) | (bf16rn(xa.w) << 16);
      unsigned p2 = bf16rn(xb.x) | (bf16rn(xb.y) << 16);
      unsigned p3 = bf16rn(xb.z) | (bf16rn(xb.w) << 16);
      xh[kc] = u4_frag(make_uint4(p0, p1, p2, p3));
    }

    f32x4 acc[8];
#pragma unroll
    for (int n = 0; n < 8; ++n) acc[n] = zero4;
#pragma unroll
    for (int n = 0; n < 8; ++n){
      const char* rp = smem + (n * 16 + m) * 256;
      s16x8 B0 = *reinterpret_cast<const s16x8*>(rp + ((0 * 64 + g * 16) ^ sw));
      s16x8 B1 = *reinterpret_cast<const s16x8*>(rp + ((1 * 64 + g * 16) ^ sw));
      s16x8 B2 = *reinterpret_cast<const s16x8*>(rp + ((2 * 64 + g * 16) ^ sw));
      s16x8 B3 = *reinterpret_cast<const s16x8*>(rp + ((3 * 64 + g * 16) ^ sw));
      acc[n] = __builtin_amdgcn_mfma_f32_16x16x32_bf16(xh[0], B0, acc[n], 0, 0, 0);
      acc[n] = __builtin_amdgcn_mfma_f32_16x16x32_bf16(xh[1], B1, acc[n], 0, 0, 0);
      acc[n] = __builtin_amdgcn_mfma_f32_16x16x32_bf16(xh[2], B2, acc[n], 0, 0, 0);
      acc[n] = __builtin_amdgcn_mfma_f32_16x16x32_bf16(xh[3], B3, acc[n], 0, 0, 0);
    }
#pragma unroll
    for (int n = 0; n < 8; ++n)
#pragma unroll
      for (int r = 0; r < 4; ++r)
        __builtin_nontemporal_store(acc[n][r] + ccv[n],
                                    &y[(long)(r0w + g * 4 + r) * 128 + n * 16 + m]);
  }
}

extern "C" void kernel_launch(void* const* d_in, const int* in_sizes, int n_in,
                              void* d_out, int out_size, void* d_ws, size_t ws_size,
                              hipStream_t stream)
{
  const float* x1  = (const float*)d_in[0];
  const float* x2  = (const float*)d_in[1];
  const float* Wq  = (const float*)d_in[2];
  const float* bq  = (const float*)d_in[3];
  const float* Wk  = (const float*)d_in[4];
  const float* bk  = (const float*)d_in[5];
  const float* Wv1 = (const float*)d_in[6];
  const float* bv1 = (const float*)d_in[7];
  const float* Wv2 = (const float*)d_in[8];
  const float* bv2 = (const float*)d_in[9];
  const float* gm  = (const float*)d_in[10];
  const float* bt  = (const float*)d_in[11];
  float* out = (float*)d_out;
  float* ws  = (float*)d_ws;

  long wsf = (long)(ws_size / 4);
  int NB = (int)((wsf - 500000) / 49408);   // per-block partials: 3*16384 + 256 floats
  if (NB > 256) NB = 256;
  if (NB < 1) NB = 1;

  float* partG = ws;                              // NB * 49152
  float* partS = partG + (long)NB * 49152;        // NB * 256
  float* part2 = partS + (long)NB * 256;          // RSEG * 49152 = 393216
  float* G     = part2 + (long)RSEG * GRAM_FLOATS;// G11 | G12 | G22
  float* sv    = G + 49152;                       // s1 | s2
  float* attn  = sv + 256;                        // 16384
  unsigned short* AhT = (unsigned short*)(attn + 16384);  // A1''ᵀ | A2''ᵀ as bf16
  float* cc    = (float*)(AhT + 32768);           // c1'' | c2''

  k_gram   <<<NB,       512, 0, stream>>>(x1, x2, partG, partS, NB);
  k_reduceA<<<RSEG*48,  256, 0, stream>>>(partG, part2, NB);
  k_reduceB<<<49,       256, 0, stream>>>(part2, partS, G, sv, NB);
  k_attnS  <<<128,      128, 0, stream>>>(G + 16384, Wq, Wk, sv, bq, bk, attn);
  k_stats2 <<<256,      128, 0, stream>>>(attn, G, sv, Wq, Wk, bq, bk, bv1, bv2, Wv1, Wv2, gm, bt, AhT, cc);
  k_apply  <<<2048,     256, 0, stream>>>(x1, x2, AhT, cc, out);
}